// Round 1
// baseline (2648.542 us; speedup 1.0000x reference)
//
#include <hip/hip_runtime.h>
#include <math.h>

#define DD 512
#define NA_TOT 22904
#define NR_TOT 2904

// Per-batch row offsets (deterministic from the reference's _counts()).
__constant__ int c_aoff[17] = {0,1024,2145,3363,4678,6090,7599,9205,10908,12708,
                               14605,16599,17666,18830,20091,21449,22904};
__constant__ int c_roff[17] = {0,128,293,495,734,882,1067,1289,1420,1588,
                               1793,2035,2186,2374,2599,2733,2904};

__device__ __forceinline__ float wred_max(float x){
#pragma unroll
  for (int o = 32; o > 0; o >>= 1) x = fmaxf(x, __shfl_xor(x, o, 64));
  return x;
}
__device__ __forceinline__ float wred_sum(float x){
#pragma unroll
  for (int o = 32; o > 0; o >>= 1) x += __shfl_xor(x, o, 64);
  return x;
}

// ---------------- GEMM: Y[M,512] = X[M,512] @ W[512,512]^T + bias ----------------
// 64x64 tile, BK=16, 256 threads, 4x4 micro-tile per thread, float4 everywhere.
__global__ __launch_bounds__(256) void gemm_bt(const float* __restrict__ X,
                                               const float* __restrict__ W,
                                               const float* __restrict__ bias,
                                               float* __restrict__ Y, int M)
{
  __shared__ float As[16][68];   // As[k][m], pad 68 for bank spread + f4 align
  __shared__ float Bs[16][68];   // Bs[k][n]
  const int m0 = blockIdx.x * 64;
  const int n0 = blockIdx.y * 64;
  const int tid = threadIdx.x;
  const int ty = tid >> 4;       // 0..15 -> rows m0+ty*4..+3
  const int tx = tid & 15;       // 0..15 -> cols n0+tx*4..+3
  const int lrow = tid >> 2;     // 0..63 (loader row)
  const int lc4 = tid & 3;       // 0..3  (loader float4 within 16-wide k slab)

  float acc[4][4];
#pragma unroll
  for (int i = 0; i < 4; ++i)
#pragma unroll
    for (int j = 0; j < 4; ++j) acc[i][j] = 0.f;

  const bool xok = (m0 + lrow) < M;
  const float* Xp = X + (size_t)(m0 + lrow) * DD + lc4 * 4;
  const float* Wp = W + (size_t)(n0 + lrow) * DD + lc4 * 4;

  for (int kb = 0; kb < DD; kb += 16) {
    float4 xv = make_float4(0.f, 0.f, 0.f, 0.f);
    if (xok) xv = *reinterpret_cast<const float4*>(Xp + kb);
    const float4 wv = *reinterpret_cast<const float4*>(Wp + kb);
    As[lc4*4+0][lrow] = xv.x; As[lc4*4+1][lrow] = xv.y;
    As[lc4*4+2][lrow] = xv.z; As[lc4*4+3][lrow] = xv.w;
    Bs[lc4*4+0][lrow] = wv.x; Bs[lc4*4+1][lrow] = wv.y;
    Bs[lc4*4+2][lrow] = wv.z; Bs[lc4*4+3][lrow] = wv.w;
    __syncthreads();
#pragma unroll
    for (int k = 0; k < 16; ++k) {
      const float4 av = *reinterpret_cast<const float4*>(&As[k][ty*4]);
      const float4 bv = *reinterpret_cast<const float4*>(&Bs[k][tx*4]);
      const float aa[4] = {av.x, av.y, av.z, av.w};
      const float bb[4] = {bv.x, bv.y, bv.z, bv.w};
#pragma unroll
      for (int i = 0; i < 4; ++i)
#pragma unroll
        for (int j = 0; j < 4; ++j) acc[i][j] = fmaf(aa[i], bb[j], acc[i][j]);
    }
    __syncthreads();
  }

  const float4 bv = *reinterpret_cast<const float4*>(bias + n0 + tx*4);
  const float badd[4] = {bv.x, bv.y, bv.z, bv.w};
#pragma unroll
  for (int i = 0; i < 4; ++i) {
    const int gm = m0 + ty*4 + i;
    if (gm < M) {
      float4 o;
      o.x = acc[i][0] + badd[0]; o.y = acc[i][1] + badd[1];
      o.z = acc[i][2] + badd[2]; o.w = acc[i][3] + badd[3];
      *reinterpret_cast<float4*>(Y + (size_t)gm * DD + n0 + tx*4) = o;
    }
  }
}

// ---------------- Flash-style varlen attention, fp32 ----------------
// grid: (q_tiles, B, H). Block 256 = 4 waves; each wave owns 12 query rows.
// Per 64-key chunk: lane k computes score(q,k); online softmax via wave
// reductions; P transposed through LDS; lane d accumulates O[q][d].
#define QT 48
__global__ __launch_bounds__(256) void attn_fused(const float* __restrict__ Q,
                                                  const float* __restrict__ K,
                                                  const float* __restrict__ V,
                                                  float* __restrict__ O, int swap)
{
  __shared__ float Qs[QT][64];
  __shared__ float Ks[64][68];   // padded: per-lane row reads (float4)
  __shared__ float Vs[64][64];   // column reads, stride 64 is conflict-free
  __shared__ float Ps[QT][64];
  const int* qo = swap ? c_roff : c_aoff;
  const int* ko = swap ? c_aoff : c_roff;
  const int b = blockIdx.y;
  const int h = blockIdx.z;
  const int Lq = qo[b+1] - qo[b];
  const int Lk = ko[b+1] - ko[b];
  const int q0 = blockIdx.x * QT;
  if (q0 >= Lq) return;
  const int tid = threadIdx.x;
  const int w = tid >> 6;
  const int lane = tid & 63;
  const float* Qb = Q + (size_t)qo[b] * DD + h * 64;
  const float* Kb = K + (size_t)ko[b] * DD + h * 64;
  const float* Vb = V + (size_t)ko[b] * DD + h * 64;

  // Load Q tile, pre-scaled by 1/sqrt(64)
#pragma unroll
  for (int i = 0; i < 3; ++i) {
    const int f = tid + i * 256;        // 768 float4s = 48x64
    const int row = f >> 4, c4 = f & 15;
    float4 v = make_float4(0.f, 0.f, 0.f, 0.f);
    if (q0 + row < Lq)
      v = *reinterpret_cast<const float4*>(Qb + (size_t)(q0 + row) * DD + c4*4);
    Qs[row][c4*4+0] = v.x * 0.125f; Qs[row][c4*4+1] = v.y * 0.125f;
    Qs[row][c4*4+2] = v.z * 0.125f; Qs[row][c4*4+3] = v.w * 0.125f;
  }

  float m_run[12], l_run[12], acc[12];
#pragma unroll
  for (int q = 0; q < 12; ++q) { m_run[q] = -__builtin_inff(); l_run[q] = 0.f; acc[q] = 0.f; }

  const int nkb = (Lk + 63) >> 6;
  for (int kb = 0; kb < nkb; ++kb) {
    __syncthreads();               // previous chunk's readers done
    const int kbase = kb * 64;
#pragma unroll
    for (int i = 0; i < 4; ++i) {
      const int f = tid + i * 256;      // 1024 float4s = 64x64
      const int row = f >> 4, c4 = f & 15;
      float4 kv = make_float4(0.f,0.f,0.f,0.f), vv = make_float4(0.f,0.f,0.f,0.f);
      if (kbase + row < Lk) {
        kv = *reinterpret_cast<const float4*>(Kb + (size_t)(kbase + row) * DD + c4*4);
        vv = *reinterpret_cast<const float4*>(Vb + (size_t)(kbase + row) * DD + c4*4);
      }
      Ks[row][c4*4+0] = kv.x; Ks[row][c4*4+1] = kv.y;
      Ks[row][c4*4+2] = kv.z; Ks[row][c4*4+3] = kv.w;
      Vs[row][c4*4+0] = vv.x; Vs[row][c4*4+1] = vv.y;
      Vs[row][c4*4+2] = vv.z; Vs[row][c4*4+3] = vv.w;
    }
    __syncthreads();
    const bool kvalid = (kbase + lane) < Lk;
    const float4* kr = reinterpret_cast<const float4*>(&Ks[lane][0]);
#pragma unroll
    for (int q = 0; q < 12; ++q) {
      const int qq = w * 12 + q;
      const float4* qr = reinterpret_cast<const float4*>(&Qs[qq][0]);
      float s = 0.f;
#pragma unroll
      for (int d4 = 0; d4 < 16; ++d4) {
        const float4 a = qr[d4];       // broadcast
        const float4 kk = kr[d4];      // per-lane row
        s = fmaf(a.x, kk.x, s); s = fmaf(a.y, kk.y, s);
        s = fmaf(a.z, kk.z, s); s = fmaf(a.w, kk.w, s);
      }
      if (!kvalid) s = -__builtin_inff();
      const float cmax = wred_max(s);
      const float mnew = fmaxf(m_run[q], cmax);
      const float p = __expf(s - mnew);            // 0 for masked lanes
      const float csum = wred_sum(p);
      const float alpha = __expf(m_run[q] - mnew); // 0 on first chunk
      m_run[q] = mnew;
      l_run[q] = l_run[q] * alpha + csum;
      Ps[qq][lane] = p;
      __builtin_amdgcn_wave_barrier();             // order intra-wave LDS RAW
      float a2 = acc[q] * alpha;
      const float4* pr = reinterpret_cast<const float4*>(&Ps[qq][0]);
#pragma unroll
      for (int k4 = 0; k4 < 16; ++k4) {
        const float4 p4 = pr[k4];                  // broadcast
        a2 = fmaf(p4.x, Vs[k4*4+0][lane], a2);
        a2 = fmaf(p4.y, Vs[k4*4+1][lane], a2);
        a2 = fmaf(p4.z, Vs[k4*4+2][lane], a2);
        a2 = fmaf(p4.w, Vs[k4*4+3][lane], a2);
      }
      acc[q] = a2;
    }
  }
#pragma unroll
  for (int q = 0; q < 12; ++q) {
    const int qq = w * 12 + q;
    if (q0 + qq < Lq)
      O[((size_t)(qo[b] + q0 + qq)) * DD + h * 64 + lane] = acc[q] / l_run[q];
  }
}

// ---------------- LayerNorm (in-place on d_out) + residual ----------------
__global__ __launch_bounds__(256) void ln_res(float* __restrict__ Y,
    const float* __restrict__ atom_node, const float* __restrict__ res_node,
    const float* __restrict__ ag, const float* __restrict__ ab,
    const float* __restrict__ rg, const float* __restrict__ rb)
{
  const int row = blockIdx.x * 4 + (threadIdx.x >> 6);
  const int lane = threadIdx.x & 63;
  if (row >= NA_TOT + NR_TOT) return;
  const float* g; const float* bb; const float* resid;
  if (row < NA_TOT) { g = ag; bb = ab; resid = atom_node + (size_t)row * DD; }
  else { g = rg; bb = rb; resid = res_node + (size_t)(row - NA_TOT) * DD; }
  float* y = Y + (size_t)row * DD;
  const float4 x0 = *reinterpret_cast<const float4*>(y + lane*4);
  const float4 x1 = *reinterpret_cast<const float4*>(y + 256 + lane*4);
  const float xv[8] = {x0.x,x0.y,x0.z,x0.w,x1.x,x1.y,x1.z,x1.w};
  float s = 0.f;
#pragma unroll
  for (int i = 0; i < 8; ++i) s += xv[i];
  s = wred_sum(s);
  const float mean = s * (1.f/512.f);
  float vs = 0.f;
#pragma unroll
  for (int i = 0; i < 8; ++i) { const float d = xv[i] - mean; vs = fmaf(d, d, vs); }
  vs = wred_sum(vs) * (1.f/512.f);
  const float inv = rsqrtf(vs + 1e-5f);
  const float4 g0 = *reinterpret_cast<const float4*>(g + lane*4);
  const float4 g1 = *reinterpret_cast<const float4*>(g + 256 + lane*4);
  const float4 b0 = *reinterpret_cast<const float4*>(bb + lane*4);
  const float4 b1 = *reinterpret_cast<const float4*>(bb + 256 + lane*4);
  const float4 r0 = *reinterpret_cast<const float4*>(resid + lane*4);
  const float4 r1 = *reinterpret_cast<const float4*>(resid + 256 + lane*4);
  float4 o0, o1;
  o0.x = (x0.x-mean)*inv*g0.x + b0.x + r0.x;
  o0.y = (x0.y-mean)*inv*g0.y + b0.y + r0.y;
  o0.z = (x0.z-mean)*inv*g0.z + b0.z + r0.z;
  o0.w = (x0.w-mean)*inv*g0.w + b0.w + r0.w;
  o1.x = (x1.x-mean)*inv*g1.x + b1.x + r1.x;
  o1.y = (x1.y-mean)*inv*g1.y + b1.y + r1.y;
  o1.z = (x1.z-mean)*inv*g1.z + b1.z + r1.z;
  o1.w = (x1.w-mean)*inv*g1.w + b1.w + r1.w;
  *reinterpret_cast<float4*>(y + lane*4) = o0;
  *reinterpret_cast<float4*>(y + 256 + lane*4) = o1;
}

extern "C" void kernel_launch(void* const* d_in, const int* in_sizes, int n_in,
                              void* d_out, int out_size, void* d_ws, size_t ws_size,
                              hipStream_t stream) {
  (void)in_sizes; (void)n_in; (void)out_size; (void)ws_size;
  const float* atom_node = (const float*)d_in[0];
  const float* res_node  = (const float*)d_in[1];
  const float* r2a_in_w  = (const float*)d_in[2];
  const float* r2a_in_b  = (const float*)d_in[3];
  const float* r2a_out_w = (const float*)d_in[4];
  const float* r2a_out_b = (const float*)d_in[5];
  const float* a2r_in_w  = (const float*)d_in[6];
  const float* a2r_in_b  = (const float*)d_in[7];
  const float* a2r_out_w = (const float*)d_in[8];
  const float* a2r_out_b = (const float*)d_in[9];
  const float* atom_ln_g = (const float*)d_in[10];
  const float* atom_ln_b = (const float*)d_in[11];
  const float* res_ln_g  = (const float*)d_in[12];
  const float* res_ln_b  = (const float*)d_in[13];

  float* out = (float*)d_out;
  float* ws  = (float*)d_ws;
  const size_t NAD = (size_t)NA_TOT * DD;   // 11,726,848
  const size_t NRD = (size_t)NR_TOT * DD;   //  1,486,848
  // ws layout (peak 2*NAD + 2*NRD floats = 105.7 MB), phase-reused:
  float* Q1 = ws;                 // [NAD]  later reused as K2
  float* O1 = ws + NAD;           // [NAD]  later reused as V2
  float* K1 = ws + 2*NAD;         // [NRD]  later reused as Q2
  float* V1 = ws + 2*NAD + NRD;   // [NRD]  later reused as O2
  float* K2 = Q1; float* V2 = O1; float* Q2 = K1; float* O2 = V1;
  float* atom_upd = out;          // staged in d_out, LN'd in place at the end
  float* res_upd  = out + NAD;

  const dim3 blk(256);
  const int gma = (NA_TOT + 63) / 64;  // 358
  const int gmr = (NR_TOT + 63) / 64;  // 46

  // --- mha1 (res -> atom): projections
  gemm_bt<<<dim3(gma, 8), blk, 0, stream>>>(atom_node, r2a_in_w,            r2a_in_b,        Q1, NA_TOT);
  gemm_bt<<<dim3(gmr, 8), blk, 0, stream>>>(res_node,  r2a_in_w + 262144,   r2a_in_b + 512,  K1, NR_TOT);
  gemm_bt<<<dim3(gmr, 8), blk, 0, stream>>>(res_node,  r2a_in_w + 524288,   r2a_in_b + 1024, V1, NR_TOT);
  // --- attention 1: queries=atoms (<=1994 rows -> 42 tiles), keys=res
  attn_fused<<<dim3(42, 16, 8), blk, 0, stream>>>(Q1, K1, V1, O1, 0);
  // --- out-proj 1 -> atom_upd (in d_out)
  gemm_bt<<<dim3(gma, 8), blk, 0, stream>>>(O1, r2a_out_w, r2a_out_b, atom_upd, NA_TOT);

  // --- mha2 (atom -> res): projections (K/V from atom_upd)
  gemm_bt<<<dim3(gmr, 8), blk, 0, stream>>>(res_node, a2r_in_w,           a2r_in_b,        Q2, NR_TOT);
  gemm_bt<<<dim3(gma, 8), blk, 0, stream>>>(atom_upd, a2r_in_w + 262144,  a2r_in_b + 512,  K2, NA_TOT);
  gemm_bt<<<dim3(gma, 8), blk, 0, stream>>>(atom_upd, a2r_in_w + 524288,  a2r_in_b + 1024, V2, NA_TOT);
  // --- attention 2: queries=res (<=242 rows -> 6 tiles), keys=atoms
  attn_fused<<<dim3(6, 16, 8), blk, 0, stream>>>(Q2, K2, V2, O2, 1);
  // --- out-proj 2 -> res_upd (in d_out)
  gemm_bt<<<dim3(gmr, 8), blk, 0, stream>>>(O2, a2r_out_w, a2r_out_b, res_upd, NR_TOT);

  // --- LayerNorm in place + residual add
  ln_res<<<dim3((NA_TOT + NR_TOT) / 4), blk, 0, stream>>>(
      out, atom_node, res_node, atom_ln_g, atom_ln_b, res_ln_g, res_ln_b);
}

// Round 2
// 512.391 us; speedup vs baseline: 5.1690x; 5.1690x over previous
//
#include <hip/hip_runtime.h>
#include <hip/hip_bf16.h>
#include <math.h>

#define DD 512
#define NA_TOT 22904
#define NR_TOT 2904

// Per-batch row offsets (deterministic from the reference's _counts()).
__constant__ int c_aoff[17] = {0,1024,2145,3363,4678,6090,7599,9205,10908,12708,
                               14605,16599,17666,18830,20091,21449,22904};
__constant__ int c_roff[17] = {0,128,293,495,734,882,1067,1289,1420,1588,
                               1793,2035,2186,2374,2599,2733,2904};

typedef __attribute__((ext_vector_type(8))) short short8;
typedef __attribute__((ext_vector_type(4))) float f32x4;
typedef __attribute__((ext_vector_type(4))) unsigned short ushort4v;

__device__ __forceinline__ unsigned short f2bf(float f) {
  __hip_bfloat16 h = __float2bfloat16(f);   // RNE
  return *reinterpret_cast<unsigned short*>(&h);
}

__device__ __forceinline__ float wred_sum(float x){
#pragma unroll
  for (int o = 32; o > 0; o >>= 1) x += __shfl_xor(x, o, 64);
  return x;
}

// ================= MFMA GEMM: Y[M,512] = X[M,512] @ W[512,512]^T + bias ========
// 128x128 tile, BK=32, 256 threads (4 waves, 2x2), 4x4 MFMA frags per wave.
// LDS bf16 tiles with XOR swizzle (el ^= (row&7)<<3): conflict-free b128 reads.
template<int IN_BF16, int OUT_BF16>
__global__ __launch_bounds__(256) void gemm_mfma(const void* __restrict__ Xv,
                                                 const float* __restrict__ W,
                                                 const float* __restrict__ bias,
                                                 void* __restrict__ Yv, int M)
{
  __shared__ unsigned short Xs[128*32];
  __shared__ unsigned short Ws[128*32];
  const int tid = threadIdx.x;
  const int lane = tid & 63;
  const int w = tid >> 6;
  const int m0 = blockIdx.x * 128;
  const int n0 = blockIdx.y * 128;
  const int wm = (w & 1) * 64;
  const int wn = (w >> 1) * 64;
  const int la = lane & 15, lg = lane >> 4;

  f32x4 acc[4][4];
#pragma unroll
  for (int i = 0; i < 4; ++i)
#pragma unroll
    for (int j = 0; j < 4; ++j) acc[i][j] = (f32x4){0.f,0.f,0.f,0.f};

  // hoisted fragment LDS offsets (in ushort elements)
  int elA[4], elB[4];
#pragma unroll
  for (int i = 0; i < 4; ++i) {
    const int r = wm + i*16 + la;
    elA[i] = (r*32 + lg*8) ^ ((r & 7) << 3);
  }
#pragma unroll
  for (int j = 0; j < 4; ++j) {
    const int r = wn + j*16 + la;
    elB[j] = (r*32 + lg*8) ^ ((r & 7) << 3);
  }

  for (int kb = 0; kb < DD; kb += 32) {
    __syncthreads();
    if (IN_BF16) {
      const unsigned short* X = (const unsigned short*)Xv;
#pragma unroll
      for (int p = 0; p < 2; ++p) {
        const int idx = tid + p*256;          // 512 x 16B = 128x32 bf16
        const int row = idx >> 2, c8 = (idx & 3) * 8;
        short8 v = {0,0,0,0,0,0,0,0};
        if (m0 + row < M)
          v = *reinterpret_cast<const short8*>(X + (size_t)(m0+row)*DD + kb + c8);
        const int el = (row*32 + c8) ^ ((row & 7) << 3);
        *reinterpret_cast<short8*>(&Xs[el]) = v;
      }
    } else {
      const float* X = (const float*)Xv;
#pragma unroll
      for (int p = 0; p < 4; ++p) {
        const int idx = tid + p*256;          // 1024 x float4 = 128x32 f32
        const int row = idx >> 3, c4 = (idx & 7) * 4;
        float4 v = make_float4(0.f,0.f,0.f,0.f);
        if (m0 + row < M)
          v = *reinterpret_cast<const float4*>(X + (size_t)(m0+row)*DD + kb + c4);
        ushort4v o = { f2bf(v.x), f2bf(v.y), f2bf(v.z), f2bf(v.w) };
        const int el = (row*32 + c4) ^ ((row & 7) << 3);
        *reinterpret_cast<ushort4v*>(&Xs[el]) = o;
      }
    }
#pragma unroll
    for (int p = 0; p < 4; ++p) {
      const int idx = tid + p*256;
      const int row = idx >> 3, c4 = (idx & 7) * 4;
      const float4 v = *reinterpret_cast<const float4*>(W + (size_t)(n0+row)*DD + kb + c4);
      ushort4v o = { f2bf(v.x), f2bf(v.y), f2bf(v.z), f2bf(v.w) };
      const int el = (row*32 + c4) ^ ((row & 7) << 3);
      *reinterpret_cast<ushort4v*>(&Ws[el]) = o;
    }
    __syncthreads();

    short8 af[4], bfr[4];
#pragma unroll
    for (int i = 0; i < 4; ++i) af[i] = *reinterpret_cast<const short8*>(&Xs[elA[i]]);
#pragma unroll
    for (int j = 0; j < 4; ++j) bfr[j] = *reinterpret_cast<const short8*>(&Ws[elB[j]]);
#pragma unroll
    for (int i = 0; i < 4; ++i)
#pragma unroll
      for (int j = 0; j < 4; ++j)
        acc[i][j] = __builtin_amdgcn_mfma_f32_16x16x32_bf16(af[i], bfr[j], acc[i][j], 0, 0, 0);
  }

  // epilogue: D[m][n], m = wm+i*16+lg*4+r, n = wn+j*16+la
#pragma unroll
  for (int j = 0; j < 4; ++j) {
    const int n = n0 + wn + j*16 + la;
    const float bj = bias[n];
#pragma unroll
    for (int i = 0; i < 4; ++i) {
#pragma unroll
      for (int r = 0; r < 4; ++r) {
        const int m = m0 + wm + i*16 + lg*4 + r;
        if (m < M) {
          const float val = acc[i][j][r] + bj;
          if (OUT_BF16) ((unsigned short*)Yv)[(size_t)m*DD + n] = f2bf(val);
          else          ((float*)Yv)[(size_t)m*DD + n] = val;
        }
      }
    }
  }
}

// ================= MFMA flash attention (bf16 in/out, fp32 accum) ==============
// grid (qtiles, B, H); block 256 = 4 waves; wave w owns q-rows q0+16w .. +15.
// Per 32-key chunk: S = Q.K^T via 4 MFMAs (A=Q frags, B=K^T frags direct from
// global); online softmax in C-layout; P -> LDS -> A-frag; O += P.V via 4 MFMAs
// with V transposed into shared LDS.
__global__ __launch_bounds__(256) void attn_mfma(const unsigned short* __restrict__ Q,
                                                 const unsigned short* __restrict__ K,
                                                 const unsigned short* __restrict__ V,
                                                 unsigned short* __restrict__ O, int swap)
{
  __shared__ unsigned short Vt[64*40];       // Vt[d*40 + k] = V[kbase+k][d]
  __shared__ unsigned short Pl[4][16*40];    // per-wave P[q*40 + k]
  const int* qo = swap ? c_roff : c_aoff;
  const int* ko = swap ? c_aoff : c_roff;
  const int b = blockIdx.y, h = blockIdx.z;
  const int Lq = qo[b+1]-qo[b], Lk = ko[b+1]-ko[b];
  const int q0 = blockIdx.x * 64;
  if (q0 >= Lq) return;
  const int tid = threadIdx.x, w = tid >> 6, lane = tid & 63;
  const int la = lane & 15, lg = lane >> 4;
  const unsigned short* Qb = Q + (size_t)qo[b]*DD + h*64;
  const unsigned short* Kb = K + (size_t)ko[b]*DD + h*64;
  const unsigned short* Vb = V + (size_t)ko[b]*DD + h*64;

  // Q A-frags: A[m=la][k=lg*8+e], k-chunks d 0..31 / 32..63
  short8 qf[2];
  {
    const int qrow = q0 + w*16 + la;
    if (qrow < Lq) {
      qf[0] = *reinterpret_cast<const short8*>(Qb + (size_t)qrow*DD + lg*8);
      qf[1] = *reinterpret_cast<const short8*>(Qb + (size_t)qrow*DD + 32 + lg*8);
    } else {
      qf[0] = (short8){0,0,0,0,0,0,0,0}; qf[1] = (short8){0,0,0,0,0,0,0,0};
    }
  }

  f32x4 acc[4];
#pragma unroll
  for (int j = 0; j < 4; ++j) acc[j] = (f32x4){0.f,0.f,0.f,0.f};
  float m_run[4] = {-1e30f,-1e30f,-1e30f,-1e30f};
  float lsum[4]  = {0.f,0.f,0.f,0.f};

  const int skk = tid & 31;          // staging: key within chunk
  const int sd0 = (tid >> 5) * 8;    // staging: d base
  const int nkc = (Lk + 31) >> 5;

  for (int kc = 0; kc < nkc; ++kc) {
    const int kbase = kc * 32;
    __syncthreads();                 // Vt free (prev chunk's readers done)
    {
      short8 vv = {0,0,0,0,0,0,0,0};
      if (kbase + skk < Lk)
        vv = *reinterpret_cast<const short8*>(Vb + (size_t)(kbase+skk)*DD + sd0);
#pragma unroll
      for (int e = 0; e < 8; ++e) Vt[(sd0+e)*40 + skk] = (unsigned short)vv[e];
    }
    // K^T B-frags: B[k=lg*8+e][n=la] = K[kbase + kh*16 + la][dchunk*32 + lg*8 + e]
    const int kr0 = kbase + la, kr1 = kbase + 16 + la;
    const short8 kf00 = *reinterpret_cast<const short8*>(Kb + (size_t)kr0*DD + lg*8);
    const short8 kf01 = *reinterpret_cast<const short8*>(Kb + (size_t)kr0*DD + 32 + lg*8);
    const short8 kf10 = *reinterpret_cast<const short8*>(Kb + (size_t)kr1*DD + lg*8);
    const short8 kf11 = *reinterpret_cast<const short8*>(Kb + (size_t)kr1*DD + 32 + lg*8);
    __syncthreads();                 // Vt ready

    f32x4 S0 = (f32x4){0.f,0.f,0.f,0.f}, S1 = (f32x4){0.f,0.f,0.f,0.f};
    S0 = __builtin_amdgcn_mfma_f32_16x16x32_bf16(qf[0], kf00, S0, 0, 0, 0);
    S0 = __builtin_amdgcn_mfma_f32_16x16x32_bf16(qf[1], kf01, S0, 0, 0, 0);
    S1 = __builtin_amdgcn_mfma_f32_16x16x32_bf16(qf[0], kf10, S1, 0, 0, 0);
    S1 = __builtin_amdgcn_mfma_f32_16x16x32_bf16(qf[1], kf11, S1, 0, 0, 0);

    const bool ok0 = (kbase + la) < Lk, ok1 = (kbase + 16 + la) < Lk;
    float s0[4], s1[4], cm[4];
#pragma unroll
    for (int r = 0; r < 4; ++r) {
      s0[r] = ok0 ? S0[r]*0.125f : -1e30f;
      s1[r] = ok1 ? S1[r]*0.125f : -1e30f;
      cm[r] = fmaxf(s0[r], s1[r]);
    }
#pragma unroll
    for (int msk = 1; msk <= 8; msk <<= 1)
#pragma unroll
      for (int r = 0; r < 4; ++r) cm[r] = fmaxf(cm[r], __shfl_xor(cm[r], msk, 64));

    float al[4];
#pragma unroll
    for (int r = 0; r < 4; ++r) {
      const float mn = fmaxf(m_run[r], cm[r]);
      al[r] = __expf(m_run[r] - mn);
      m_run[r] = mn;
      s0[r] = __expf(s0[r] - mn);
      s1[r] = __expf(s1[r] - mn);
      lsum[r] = lsum[r]*al[r] + s0[r] + s1[r];
    }
#pragma unroll
    for (int j = 0; j < 4; ++j)
#pragma unroll
      for (int r = 0; r < 4; ++r) acc[j][r] *= al[r];

    // P (C-layout) -> LDS -> A-frag
#pragma unroll
    for (int r = 0; r < 4; ++r) {
      const int q = lg*4 + r;
      Pl[w][q*40 + la]      = f2bf(s0[r]);
      Pl[w][q*40 + 16 + la] = f2bf(s1[r]);
    }
    __builtin_amdgcn_wave_barrier();
    const short8 pf = *reinterpret_cast<const short8*>(&Pl[w][la*40 + lg*8]);
#pragma unroll
    for (int j = 0; j < 4; ++j) {
      const short8 vf = *reinterpret_cast<const short8*>(&Vt[(16*j + la)*40 + lg*8]);
      acc[j] = __builtin_amdgcn_mfma_f32_16x16x32_bf16(pf, vf, acc[j], 0, 0, 0);
    }
  }

  // row-sum across the 16 key-lanes, then store O (bf16)
#pragma unroll
  for (int msk = 1; msk <= 8; msk <<= 1)
#pragma unroll
    for (int r = 0; r < 4; ++r) lsum[r] += __shfl_xor(lsum[r], msk, 64);
#pragma unroll
  for (int r = 0; r < 4; ++r) {
    const float inv = 1.f / lsum[r];
    const int qrow = q0 + w*16 + lg*4 + r;
    if (qrow < Lq) {
      const size_t base = (size_t)(qo[b] + qrow)*DD + h*64;
#pragma unroll
      for (int j = 0; j < 4; ++j) O[base + 16*j + la] = f2bf(acc[j][r] * inv);
    }
  }
}

// ---------------- LayerNorm (in-place on d_out) + residual ----------------
__global__ __launch_bounds__(256) void ln_res(float* __restrict__ Y,
    const float* __restrict__ atom_node, const float* __restrict__ res_node,
    const float* __restrict__ ag, const float* __restrict__ ab,
    const float* __restrict__ rg, const float* __restrict__ rb)
{
  const int row = blockIdx.x * 4 + (threadIdx.x >> 6);
  const int lane = threadIdx.x & 63;
  if (row >= NA_TOT + NR_TOT) return;
  const float* g; const float* bb; const float* resid;
  if (row < NA_TOT) { g = ag; bb = ab; resid = atom_node + (size_t)row * DD; }
  else { g = rg; bb = rb; resid = res_node + (size_t)(row - NA_TOT) * DD; }
  float* y = Y + (size_t)row * DD;
  const float4 x0 = *reinterpret_cast<const float4*>(y + lane*4);
  const float4 x1 = *reinterpret_cast<const float4*>(y + 256 + lane*4);
  const float xv[8] = {x0.x,x0.y,x0.z,x0.w,x1.x,x1.y,x1.z,x1.w};
  float s = 0.f;
#pragma unroll
  for (int i = 0; i < 8; ++i) s += xv[i];
  s = wred_sum(s);
  const float mean = s * (1.f/512.f);
  float vs = 0.f;
#pragma unroll
  for (int i = 0; i < 8; ++i) { const float d = xv[i] - mean; vs = fmaf(d, d, vs); }
  vs = wred_sum(vs) * (1.f/512.f);
  const float inv = rsqrtf(vs + 1e-5f);
  const float4 g0 = *reinterpret_cast<const float4*>(g + lane*4);
  const float4 g1 = *reinterpret_cast<const float4*>(g + 256 + lane*4);
  const float4 b0 = *reinterpret_cast<const float4*>(bb + lane*4);
  const float4 b1 = *reinterpret_cast<const float4*>(bb + 256 + lane*4);
  const float4 r0 = *reinterpret_cast<const float4*>(resid + lane*4);
  const float4 r1 = *reinterpret_cast<const float4*>(resid + 256 + lane*4);
  float4 o0, o1;
  o0.x = (x0.x-mean)*inv*g0.x + b0.x + r0.x;
  o0.y = (x0.y-mean)*inv*g0.y + b0.y + r0.y;
  o0.z = (x0.z-mean)*inv*g0.z + b0.z + r0.z;
  o0.w = (x0.w-mean)*inv*g0.w + b0.w + r0.w;
  o1.x = (x1.x-mean)*inv*g1.x + b1.x + r1.x;
  o1.y = (x1.y-mean)*inv*g1.y + b1.y + r1.y;
  o1.z = (x1.z-mean)*inv*g1.z + b1.z + r1.z;
  o1.w = (x1.w-mean)*inv*g1.w + b1.w + r1.w;
  *reinterpret_cast<float4*>(y + lane*4) = o0;
  *reinterpret_cast<float4*>(y + 256 + lane*4) = o1;
}

extern "C" void kernel_launch(void* const* d_in, const int* in_sizes, int n_in,
                              void* d_out, int out_size, void* d_ws, size_t ws_size,
                              hipStream_t stream) {
  (void)in_sizes; (void)n_in; (void)out_size; (void)ws_size;
  const float* atom_node = (const float*)d_in[0];
  const float* res_node  = (const float*)d_in[1];
  const float* r2a_in_w  = (const float*)d_in[2];
  const float* r2a_in_b  = (const float*)d_in[3];
  const float* r2a_out_w = (const float*)d_in[4];
  const float* r2a_out_b = (const float*)d_in[5];
  const float* a2r_in_w  = (const float*)d_in[6];
  const float* a2r_in_b  = (const float*)d_in[7];
  const float* a2r_out_w = (const float*)d_in[8];
  const float* a2r_out_b = (const float*)d_in[9];
  const float* atom_ln_g = (const float*)d_in[10];
  const float* atom_ln_b = (const float*)d_in[11];
  const float* res_ln_g  = (const float*)d_in[12];
  const float* res_ln_b  = (const float*)d_in[13];

  float* out = (float*)d_out;
  unsigned short* wsb = (unsigned short*)d_ws;
  const size_t NAD = (size_t)NA_TOT * DD;   // 11,726,848
  const size_t NRD = (size_t)NR_TOT * DD;   //  1,486,848
  // bf16 ws layout (peak ~26.4 MB), phase-reused:
  unsigned short* Q1 = wsb;                 // [NAD]  -> reused as K2
  unsigned short* O1 = wsb + NAD;           // [NAD]  -> reused as V2
  unsigned short* K1 = wsb + 2*NAD;         // [NRD]  -> reused as Q2
  unsigned short* V1 = wsb + 2*NAD + NRD;   // [NRD]  -> reused as O2
  unsigned short* K2 = Q1; unsigned short* V2 = O1;
  unsigned short* Q2 = K1; unsigned short* O2 = V1;
  float* atom_upd = out;          // staged in d_out, LN'd in place at the end
  float* res_upd  = out + NAD;

  const dim3 blk(256);
  const int gma = (NA_TOT + 127) / 128;  // 179
  const int gmr = (NR_TOT + 127) / 128;  // 23

  // --- mha1 (res -> atom): projections (bf16 out)
  gemm_mfma<0,1><<<dim3(gma,4), blk, 0, stream>>>(atom_node, r2a_in_w,          r2a_in_b,        Q1, NA_TOT);
  gemm_mfma<0,1><<<dim3(gmr,4), blk, 0, stream>>>(res_node,  r2a_in_w + 262144, r2a_in_b + 512,  K1, NR_TOT);
  gemm_mfma<0,1><<<dim3(gmr,4), blk, 0, stream>>>(res_node,  r2a_in_w + 524288, r2a_in_b + 1024, V1, NR_TOT);
  // --- attention 1: queries=atoms (<=1994 rows -> 32 tiles of 64), keys=res
  attn_mfma<<<dim3(32,16,8), blk, 0, stream>>>(Q1, K1, V1, O1, 0);
  // --- out-proj 1 (bf16 in, fp32 out) -> atom_upd (in d_out)
  gemm_mfma<1,0><<<dim3(gma,4), blk, 0, stream>>>(O1, r2a_out_w, r2a_out_b, atom_upd, NA_TOT);

  // --- mha2 (atom -> res): projections
  gemm_mfma<0,1><<<dim3(gmr,4), blk, 0, stream>>>(res_node, a2r_in_w,          a2r_in_b,        Q2, NR_TOT);
  gemm_mfma<0,1><<<dim3(gma,4), blk, 0, stream>>>(atom_upd, a2r_in_w + 262144, a2r_in_b + 512,  K2, NA_TOT);
  gemm_mfma<0,1><<<dim3(gma,4), blk, 0, stream>>>(atom_upd, a2r_in_w + 524288, a2r_in_b + 1024, V2, NA_TOT);
  // --- attention 2: queries=res (<=242 rows -> 4 tiles), keys=atoms
  attn_mfma<<<dim3(4,16,8), blk, 0, stream>>>(Q2, K2, V2, O2, 1);
  // --- out-proj 2 -> res_upd (in d_out)
  gemm_mfma<1,0><<<dim3(gmr,4), blk, 0, stream>>>(O2, a2r_out_w, a2r_out_b, res_upd, NR_TOT);

  // --- LayerNorm in place + residual add
  ln_res<<<dim3((NA_TOT + NR_TOT) / 4), blk, 0, stream>>>(
      out, atom_node, res_node, atom_ln_g, atom_ln_b, res_ln_g, res_ln_b);
}

// Round 3
// 384.132 us; speedup vs baseline: 6.8949x; 1.3339x over previous
//
#include <hip/hip_runtime.h>
#include <hip/hip_bf16.h>
#include <math.h>

#define DD 512
#define NA_TOT 22904
#define NR_TOT 2904

// Per-batch row offsets (deterministic from the reference's _counts()).
__constant__ int c_aoff[17] = {0,1024,2145,3363,4678,6090,7599,9205,10908,12708,
                               14605,16599,17666,18830,20091,21449,22904};
__constant__ int c_roff[17] = {0,128,293,495,734,882,1067,1289,1420,1588,
                               1793,2035,2186,2374,2599,2733,2904};

typedef __attribute__((ext_vector_type(8))) short short8;
typedef __attribute__((ext_vector_type(4))) float f32x4;
typedef __attribute__((ext_vector_type(4))) unsigned short ushort4v;

__device__ __forceinline__ unsigned short f2bf(float f) {
  __hip_bfloat16 h = __float2bfloat16(f);   // RNE
  return *reinterpret_cast<unsigned short*>(&h);
}

__device__ __forceinline__ float wred_sum(float x){
#pragma unroll
  for (int o = 32; o > 0; o >>= 1) x += __shfl_xor(x, o, 64);
  return x;
}

// async global->LDS, 16B per lane. LDS dest = wave-uniform base + lane*16.
__device__ __forceinline__ void gl_lds16(const unsigned short* g, unsigned short* l) {
  __builtin_amdgcn_global_load_lds(
      (const __attribute__((address_space(1))) unsigned int*)g,
      (__attribute__((address_space(3))) unsigned int*)l, 16, 0, 0);
}

// ---------------- fp32 -> bf16 pre-convert (5 segments) ----------------
__global__ __launch_bounds__(256) void cvt5(
    const float* __restrict__ s0, const float* __restrict__ s1,
    const float* __restrict__ s2, const float* __restrict__ s3,
    const float* __restrict__ s4,
    unsigned short* __restrict__ d0, unsigned short* __restrict__ d1,
    unsigned short* __restrict__ d2, unsigned short* __restrict__ d3,
    unsigned short* __restrict__ d4,
    int n0, int n1, int n2, int n3, int n4)
{
  const float* s; unsigned short* d; int n;
  switch (blockIdx.y) {
    case 0: s = s0; d = d0; n = n0; break;
    case 1: s = s1; d = d1; n = n1; break;
    case 2: s = s2; d = d2; n = n2; break;
    case 3: s = s3; d = d3; n = n3; break;
    default: s = s4; d = d4; n = n4; break;
  }
  const int i = (blockIdx.x * 256 + threadIdx.x) * 4;
  if (i < n) {
    const float4 v = *reinterpret_cast<const float4*>(s + i);
    ushort4v o = { f2bf(v.x), f2bf(v.y), f2bf(v.z), f2bf(v.w) };
    *reinterpret_cast<ushort4v*>(d + i) = o;
  }
}

// ================= MFMA GEMM: Y[M,N] = X[M,512] @ W[N,512]^T + bias ===========
// 128x128 tile, BK=64, 256 threads (4 waves 2x2), 4x4 frags/wave, 32 MFMA/K-step.
// LDS holds swizzle-order tiles: linear slot (row,cg) stores global col (cg^(row&7)).
// Fragment read at col' = col ^ ((row&7)<<3) recovers data; 2-way banks (free).
// INF32: X is fp32 (reg-staged convert); else bf16 via global_load_lds.
// OUTMODE: 0 = fp32 only, 1 = bf16 only, 2 = both.
template<int INF32, int OUTMODE>
__global__ __launch_bounds__(256) void gemm_tn(const void* __restrict__ Xv,
    const unsigned short* __restrict__ Wb, const float* __restrict__ bias,
    float* __restrict__ Yf, unsigned short* __restrict__ Yb, int M, int ldY)
{
  __shared__ unsigned short Xs[128*64];
  __shared__ unsigned short Ws[128*64];
  const int tid = threadIdx.x, lane = tid & 63, w = tid >> 6;
  const int la = lane & 15, lg = lane >> 4;
  const int m0 = blockIdx.x * 128, n0 = blockIdx.y * 128;
  const int wm = (w & 1) * 64, wn = (w >> 1) * 64;
  const int w64 = w * 64;

  f32x4 acc[4][4];
#pragma unroll
  for (int i = 0; i < 4; ++i)
#pragma unroll
    for (int j = 0; j < 4; ++j) acc[i][j] = (f32x4){0.f,0.f,0.f,0.f};

  int elA[4][2], elB[4][2];
#pragma unroll
  for (int i = 0; i < 4; ++i)
#pragma unroll
    for (int kc = 0; kc < 2; ++kc) {
      { const int r = wm + i*16 + la;
        elA[i][kc] = r*64 + ((kc*32 + lg*8) ^ ((r & 7) << 3)); }
      { const int r = wn + i*16 + la;
        elB[i][kc] = r*64 + ((kc*32 + lg*8) ^ ((r & 7) << 3)); }
    }

  for (int kb = 0; kb < DD; kb += 64) {
    __syncthreads();
#pragma unroll
    for (int p = 0; p < 4; ++p) {
      const int slot = p*256 + tid;
      const int row = slot >> 3, cg = slot & 7;
      const int col = kb + ((cg ^ (row & 7)) << 3);
      gl_lds16(Wb + (size_t)(n0 + row) * DD + col, &Ws[(p*256 + w64) * 8]);
    }
    if (INF32) {
      const float* X = (const float*)Xv;
#pragma unroll
      for (int p = 0; p < 4; ++p) {
        const int slot = p*256 + tid;
        const int row = slot >> 3, cg = slot & 7;
        const int col = kb + ((cg ^ (row & 7)) << 3);
        const int rg = min(m0 + row, M - 1);
        const float* src = X + (size_t)rg * DD + col;
        const float4 v0 = *reinterpret_cast<const float4*>(src);
        const float4 v1 = *reinterpret_cast<const float4*>(src + 4);
        short8 pk;
        pk[0] = (short)f2bf(v0.x); pk[1] = (short)f2bf(v0.y);
        pk[2] = (short)f2bf(v0.z); pk[3] = (short)f2bf(v0.w);
        pk[4] = (short)f2bf(v1.x); pk[5] = (short)f2bf(v1.y);
        pk[6] = (short)f2bf(v1.z); pk[7] = (short)f2bf(v1.w);
        *reinterpret_cast<short8*>(&Xs[slot * 8]) = pk;
      }
    } else {
      const unsigned short* X = (const unsigned short*)Xv;
#pragma unroll
      for (int p = 0; p < 4; ++p) {
        const int slot = p*256 + tid;
        const int row = slot >> 3, cg = slot & 7;
        const int col = kb + ((cg ^ (row & 7)) << 3);
        const int rg = min(m0 + row, M - 1);
        gl_lds16(X + (size_t)rg * DD + col, &Xs[(p*256 + w64) * 8]);
      }
    }
    __syncthreads();

    short8 af[4][2], bfm[4][2];
#pragma unroll
    for (int i = 0; i < 4; ++i)
#pragma unroll
      for (int kc = 0; kc < 2; ++kc) {
        af[i][kc]  = *reinterpret_cast<const short8*>(&Xs[elA[i][kc]]);
        bfm[i][kc] = *reinterpret_cast<const short8*>(&Ws[elB[i][kc]]);
      }
#pragma unroll
    for (int kc = 0; kc < 2; ++kc)
#pragma unroll
      for (int i = 0; i < 4; ++i)
#pragma unroll
        for (int j = 0; j < 4; ++j)
          acc[i][j] = __builtin_amdgcn_mfma_f32_16x16x32_bf16(af[i][kc], bfm[j][kc], acc[i][j], 0, 0, 0);
  }

#pragma unroll
  for (int j = 0; j < 4; ++j) {
    const int n = n0 + wn + j*16 + la;
    const float bj = bias[n];
#pragma unroll
    for (int i = 0; i < 4; ++i) {
      const int mbase = m0 + wm + i*16 + lg*4;
#pragma unroll
      for (int r = 0; r < 4; ++r) {
        const int m = mbase + r;
        if (m < M) {
          const float val = acc[i][j][r] + bj;
          if (OUTMODE == 0 || OUTMODE == 2) Yf[(size_t)m * ldY + n] = val;
          if (OUTMODE >= 1)                 Yb[(size_t)m * ldY + n] = f2bf(val);
        }
      }
    }
  }
}

// ================= MFMA flash attention v2 (bf16, fp32 accum) =================
// grid (qtiles, B, H); block 256 = 4 waves; wave w owns 32 q-rows (2 m-frags).
// 64-key chunks: K staged via global_load_lds into swizzled LDS (block-shared),
// V transposed into swizzled LDS; 16 QK-MFMA + 16 PV-MFMA per chunk.
template<int SWAP>
__global__ __launch_bounds__(256) void attn_v2(const unsigned short* __restrict__ Q,
                                               const unsigned short* __restrict__ K,
                                               const unsigned short* __restrict__ V,
                                               unsigned short* __restrict__ O, int ldkv)
{
  __shared__ unsigned short Ks[64*64];      // [key][d], swizzled
  __shared__ unsigned short Vt[64*64];      // [d][key], swizzled
  __shared__ unsigned short Pl[4][32*64];   // per-wave [qrow][key], swizzled
  const int* qo = SWAP ? c_roff : c_aoff;
  const int* ko = SWAP ? c_aoff : c_roff;
  const int b = blockIdx.y, h = blockIdx.z;
  const int Lq = qo[b+1]-qo[b], Lk = ko[b+1]-ko[b];
  const int q0 = blockIdx.x * 128;
  if (q0 >= Lq) return;
  const int tid = threadIdx.x, w = tid >> 6, lane = tid & 63;
  const int la = lane & 15, lg = lane >> 4;
  const unsigned short* Qb = Q + (size_t)qo[b]*DD + h*64;
  const unsigned short* Kb = K + (size_t)ko[b]*ldkv + h*64;
  const unsigned short* Vb = V + (size_t)ko[b]*ldkv + h*64;

  // Q A-frags: [i=m-frag][kc=d-chunk]; A[m=la][k=lg*8+e]
  short8 qf[2][2];
#pragma unroll
  for (int i = 0; i < 2; ++i) {
    const int qrow = q0 + w*32 + i*16 + la;
    if (qrow < Lq) {
      qf[i][0] = *reinterpret_cast<const short8*>(Qb + (size_t)qrow*DD + lg*8);
      qf[i][1] = *reinterpret_cast<const short8*>(Qb + (size_t)qrow*DD + 32 + lg*8);
    } else {
      qf[i][0] = (short8){0,0,0,0,0,0,0,0}; qf[i][1] = (short8){0,0,0,0,0,0,0,0};
    }
  }

  f32x4 acc[2][4];
#pragma unroll
  for (int i = 0; i < 2; ++i)
#pragma unroll
    for (int j = 0; j < 4; ++j) acc[i][j] = (f32x4){0.f,0.f,0.f,0.f};
  float mrun[2][4], lsum[2][4];
#pragma unroll
  for (int i = 0; i < 2; ++i)
#pragma unroll
    for (int r = 0; r < 4; ++r) { mrun[i][r] = -1e30f; lsum[i][r] = 0.f; }

  const int nkc = (Lk + 63) >> 6;
  for (int kc = 0; kc < nkc; ++kc) {
    const int kbase = kc * 64;
    __syncthreads();               // prev chunk's LDS readers done
    // K tile: 64x64, 512 slots, 2 per thread via global_load_lds
#pragma unroll
    for (int p = 0; p < 2; ++p) {
      const int slot = p*256 + tid;
      const int row = slot >> 3, cg = slot & 7;
      const int rg = min(kbase + row, Lk - 1);
      gl_lds16(Kb + (size_t)rg * ldkv + ((cg ^ (row & 7)) << 3),
               &Ks[(p*256 + w*64) * 8]);
    }
    // V transposed: thread -> key = tid&63, d-range (tid>>6)*16..+15
    {
      const int key = tid & 63, dg = tid >> 6;
      const int rg = min(kbase + key, Lk - 1);
      const unsigned short* vp = Vb + (size_t)rg * ldkv + dg*16;
      const short8 v0 = *reinterpret_cast<const short8*>(vp);
      const short8 v1 = *reinterpret_cast<const short8*>(vp + 8);
#pragma unroll
      for (int e = 0; e < 8; ++e) {
        const int d0 = dg*16 + e, d1 = dg*16 + 8 + e;
        Vt[d0*64 + (key ^ ((d0 & 7) << 3))] = (unsigned short)v0[e];
        Vt[d1*64 + (key ^ ((d1 & 7) << 3))] = (unsigned short)v1[e];
      }
    }
    __syncthreads();               // staging done (barrier drains vmcnt+lgkm)

    // QK^T: B[k=d][n=key] = Ks row-read
    short8 kf[4][2];
#pragma unroll
    for (int j = 0; j < 4; ++j)
#pragma unroll
      for (int k2 = 0; k2 < 2; ++k2) {
        const int row = j*16 + la;
        kf[j][k2] = *reinterpret_cast<const short8*>(
            &Ks[row*64 + ((k2*32 + lg*8) ^ ((row & 7) << 3))]);
      }
    f32x4 S[2][4];
#pragma unroll
    for (int i = 0; i < 2; ++i)
#pragma unroll
      for (int j = 0; j < 4; ++j) {
        f32x4 s = (f32x4){0.f,0.f,0.f,0.f};
        s = __builtin_amdgcn_mfma_f32_16x16x32_bf16(qf[i][0], kf[j][0], s, 0, 0, 0);
        s = __builtin_amdgcn_mfma_f32_16x16x32_bf16(qf[i][1], kf[j][1], s, 0, 0, 0);
        S[i][j] = s;
      }

    // online softmax (C-layout: row = i*16+lg*4+r, col = j*16+la)
    float cm[2][4];
#pragma unroll
    for (int i = 0; i < 2; ++i)
#pragma unroll
      for (int r = 0; r < 4; ++r) {
        float m = -1e30f;
#pragma unroll
        for (int j = 0; j < 4; ++j) {
          const bool ok = (kbase + j*16 + la) < Lk;
          const float s = ok ? S[i][j][r] * 0.125f : -1e30f;
          S[i][j][r] = s;
          m = fmaxf(m, s);
        }
        cm[i][r] = m;
      }
#pragma unroll
    for (int msk = 1; msk <= 8; msk <<= 1)
#pragma unroll
      for (int i = 0; i < 2; ++i)
#pragma unroll
        for (int r = 0; r < 4; ++r) cm[i][r] = fmaxf(cm[i][r], __shfl_xor(cm[i][r], msk, 64));
#pragma unroll
    for (int i = 0; i < 2; ++i)
#pragma unroll
      for (int r = 0; r < 4; ++r) {
        const float mn = fmaxf(mrun[i][r], cm[i][r]);
        const float al = __expf(mrun[i][r] - mn);
        mrun[i][r] = mn;
        float psum = 0.f;
#pragma unroll
        for (int j = 0; j < 4; ++j) {
          const float p = __expf(S[i][j][r] - mn);
          S[i][j][r] = p;
          psum += p;
        }
        lsum[i][r] = lsum[i][r] * al + psum;
#pragma unroll
        for (int j = 0; j < 4; ++j) acc[i][j][r] *= al;
      }

    // P -> per-wave LDS (swizzled), then A-frags
#pragma unroll
    for (int i = 0; i < 2; ++i)
#pragma unroll
      for (int r = 0; r < 4; ++r) {
        const int prow = i*16 + lg*4 + r;
#pragma unroll
        for (int j = 0; j < 4; ++j)
          Pl[w][prow*64 + ((j*16 + la) ^ ((prow & 7) << 3))] = f2bf(S[i][j][r]);
      }
    __builtin_amdgcn_wave_barrier();   // per-wave LDS: in-order RAW

    short8 pf[2][2], vf[2][4];
#pragma unroll
    for (int i = 0; i < 2; ++i)
#pragma unroll
      for (int k2 = 0; k2 < 2; ++k2) {
        const int row = i*16 + la;
        pf[i][k2] = *reinterpret_cast<const short8*>(
            &Pl[w][row*64 + ((k2*32 + lg*8) ^ ((row & 7) << 3))]);
      }
#pragma unroll
    for (int k2 = 0; k2 < 2; ++k2)
#pragma unroll
      for (int j = 0; j < 4; ++j) {
        const int row = j*16 + la;
        vf[k2][j] = *reinterpret_cast<const short8*>(
            &Vt[row*64 + ((k2*32 + lg*8) ^ ((row & 7) << 3))]);
      }
#pragma unroll
    for (int i = 0; i < 2; ++i)
#pragma unroll
      for (int j = 0; j < 4; ++j) {
        acc[i][j] = __builtin_amdgcn_mfma_f32_16x16x32_bf16(pf[i][0], vf[0][j], acc[i][j], 0, 0, 0);
        acc[i][j] = __builtin_amdgcn_mfma_f32_16x16x32_bf16(pf[i][1], vf[1][j], acc[i][j], 0, 0, 0);
      }
  }

  // final row-sum over the 16 la-lanes, store O
#pragma unroll
  for (int msk = 1; msk <= 8; msk <<= 1)
#pragma unroll
    for (int i = 0; i < 2; ++i)
#pragma unroll
      for (int r = 0; r < 4; ++r) lsum[i][r] += __shfl_xor(lsum[i][r], msk, 64);
#pragma unroll
  for (int i = 0; i < 2; ++i)
#pragma unroll
    for (int r = 0; r < 4; ++r) {
      const int qrow = q0 + w*32 + i*16 + lg*4 + r;
      if (qrow < Lq) {
        const float inv = 1.f / lsum[i][r];
        const size_t base = (size_t)(qo[b] + qrow)*DD + h*64;
#pragma unroll
        for (int j = 0; j < 4; ++j) O[base + j*16 + la] = f2bf(acc[i][j][r] * inv);
      }
    }
}

// ---------------- LayerNorm (in-place on d_out) + residual ----------------
__global__ __launch_bounds__(256) void ln_res(float* __restrict__ Y,
    const float* __restrict__ atom_node, const float* __restrict__ res_node,
    const float* __restrict__ ag, const float* __restrict__ ab,
    const float* __restrict__ rg, const float* __restrict__ rb)
{
  const int row = blockIdx.x * 4 + (threadIdx.x >> 6);
  const int lane = threadIdx.x & 63;
  if (row >= NA_TOT + NR_TOT) return;
  const float* g; const float* bb; const float* resid;
  if (row < NA_TOT) { g = ag; bb = ab; resid = atom_node + (size_t)row * DD; }
  else { g = rg; bb = rb; resid = res_node + (size_t)(row - NA_TOT) * DD; }
  float* y = Y + (size_t)row * DD;
  const float4 x0 = *reinterpret_cast<const float4*>(y + lane*4);
  const float4 x1 = *reinterpret_cast<const float4*>(y + 256 + lane*4);
  const float xv[8] = {x0.x,x0.y,x0.z,x0.w,x1.x,x1.y,x1.z,x1.w};
  float s = 0.f;
#pragma unroll
  for (int i = 0; i < 8; ++i) s += xv[i];
  s = wred_sum(s);
  const float mean = s * (1.f/512.f);
  float vs = 0.f;
#pragma unroll
  for (int i = 0; i < 8; ++i) { const float d = xv[i] - mean; vs = fmaf(d, d, vs); }
  vs = wred_sum(vs) * (1.f/512.f);
  const float inv = rsqrtf(vs + 1e-5f);
  const float4 g0 = *reinterpret_cast<const float4*>(g + lane*4);
  const float4 g1 = *reinterpret_cast<const float4*>(g + 256 + lane*4);
  const float4 b0 = *reinterpret_cast<const float4*>(bb + lane*4);
  const float4 b1 = *reinterpret_cast<const float4*>(bb + 256 + lane*4);
  const float4 r0 = *reinterpret_cast<const float4*>(resid + lane*4);
  const float4 r1 = *reinterpret_cast<const float4*>(resid + 256 + lane*4);
  float4 o0, o1;
  o0.x = (x0.x-mean)*inv*g0.x + b0.x + r0.x;
  o0.y = (x0.y-mean)*inv*g0.y + b0.y + r0.y;
  o0.z = (x0.z-mean)*inv*g0.z + b0.z + r0.z;
  o0.w = (x0.w-mean)*inv*g0.w + b0.w + r0.w;
  o1.x = (x1.x-mean)*inv*g1.x + b1.x + r1.x;
  o1.y = (x1.y-mean)*inv*g1.y + b1.y + r1.y;
  o1.z = (x1.z-mean)*inv*g1.z + b1.z + r1.z;
  o1.w = (x1.w-mean)*inv*g1.w + b1.w + r1.w;
  *reinterpret_cast<float4*>(y + lane*4) = o0;
  *reinterpret_cast<float4*>(y + 256 + lane*4) = o1;
}

extern "C" void kernel_launch(void* const* d_in, const int* in_sizes, int n_in,
                              void* d_out, int out_size, void* d_ws, size_t ws_size,
                              hipStream_t stream) {
  (void)in_sizes; (void)n_in; (void)out_size; (void)ws_size;
  const float* atom_node = (const float*)d_in[0];
  const float* res_node  = (const float*)d_in[1];
  const float* r2a_in_w  = (const float*)d_in[2];
  const float* r2a_in_b  = (const float*)d_in[3];
  const float* r2a_out_w = (const float*)d_in[4];
  const float* r2a_out_b = (const float*)d_in[5];
  const float* a2r_in_w  = (const float*)d_in[6];
  const float* a2r_in_b  = (const float*)d_in[7];
  const float* a2r_out_w = (const float*)d_in[8];
  const float* a2r_out_b = (const float*)d_in[9];
  const float* atom_ln_g = (const float*)d_in[10];
  const float* atom_ln_b = (const float*)d_in[11];
  const float* res_ln_g  = (const float*)d_in[12];
  const float* res_ln_b  = (const float*)d_in[13];

  float* out = (float*)d_out;
  unsigned short* wsb = (unsigned short*)d_ws;
  const size_t NAD = (size_t)NA_TOT * DD;   // 11,726,848
  const size_t NRD = (size_t)NR_TOT * DD;   //  1,486,848
  // ws layout (shorts), total ~83.5 MB, phase-reused:
  unsigned short* Q1        = wsb;                      // [NAD]
  unsigned short* O1        = wsb + NAD;                // [NAD]
  unsigned short* atomupd_b = wsb + 2*NAD;              // [NAD]
  unsigned short* res_bf    = wsb + 3*NAD;              // [NRD]
  unsigned short* KV1       = wsb + 3*NAD + NRD;        // [2*NRD]
  unsigned short* wbf       = wsb + 3*NAD + 3*NRD;      // [2,097,152]
  unsigned short* w_r2a_in  = wbf;                      // 786432
  unsigned short* w_r2a_out = wbf +  786432;            // 262144
  unsigned short* w_a2r_in  = wbf + 1048576;            // 786432
  unsigned short* w_a2r_out = wbf + 1835008;            // 262144
  // reuses (lifetimes disjoint):
  unsigned short* KV2 = wsb;            // spans Q1+O1 (both dead by GEMM6)
  unsigned short* Q2  = KV1;            // KV1 dead after attn1
  unsigned short* O2  = KV1 + NRD;
  float* atom_upd = out;                // fp32 staged in d_out, LN'd in place
  float* res_upd  = out + NAD;

  const dim3 blk(256);
  const int gma = (NA_TOT + 127) / 128;  // 179
  const int gmr = (NR_TOT + 127) / 128;  // 23

  // --- pre-convert weights + res_node to bf16
  cvt5<<<dim3(1452, 5), blk, 0, stream>>>(
      r2a_in_w, r2a_out_w, a2r_in_w, a2r_out_w, res_node,
      w_r2a_in, w_r2a_out, w_a2r_in, w_a2r_out, res_bf,
      786432, 262144, 786432, 262144, (int)NRD);

  // --- mha1 (res -> atom)
  gemm_tn<1,1><<<dim3(gma,4), blk, 0, stream>>>(atom_node, w_r2a_in,          r2a_in_b,       nullptr, Q1,  NA_TOT, 512);
  gemm_tn<0,1><<<dim3(gmr,8), blk, 0, stream>>>(res_bf,    w_r2a_in + 262144, r2a_in_b + 512, nullptr, KV1, NR_TOT, 1024);
  attn_v2<0><<<dim3(16,16,8), blk, 0, stream>>>(Q1, KV1, KV1 + 512, O1, 1024);
  gemm_tn<0,2><<<dim3(gma,4), blk, 0, stream>>>(O1, w_r2a_out, r2a_out_b, atom_upd, atomupd_b, NA_TOT, 512);

  // --- mha2 (atom -> res)
  gemm_tn<0,1><<<dim3(gmr,4), blk, 0, stream>>>(res_bf,    w_a2r_in,          a2r_in_b,       nullptr, Q2,  NR_TOT, 512);
  gemm_tn<0,1><<<dim3(gma,8), blk, 0, stream>>>(atomupd_b, w_a2r_in + 262144, a2r_in_b + 512, nullptr, KV2, NA_TOT, 1024);
  attn_v2<1><<<dim3(2,16,8), blk, 0, stream>>>(Q2, KV2, KV2 + 512, O2, 1024);
  gemm_tn<0,0><<<dim3(gmr,4), blk, 0, stream>>>(O2, w_a2r_out, a2r_out_b, res_upd, nullptr, NR_TOT, 512);

  // --- LayerNorm in place + residual add
  ln_res<<<dim3((NA_TOT + NR_TOT) / 4), blk, 0, stream>>>(
      out, atom_node, res_node, atom_ln_g, atom_ln_b, res_ln_g, res_ln_b);
}

// Round 4
// 318.338 us; speedup vs baseline: 8.3199x; 1.2067x over previous
//
#include <hip/hip_runtime.h>
#include <hip/hip_bf16.h>
#include <math.h>

#define DD 512
#define NA_TOT 22904
#define NR_TOT 2904

// Per-batch row offsets (deterministic from the reference's _counts()).
__constant__ int c_aoff[17] = {0,1024,2145,3363,4678,6090,7599,9205,10908,12708,
                               14605,16599,17666,18830,20091,21449,22904};
__constant__ int c_roff[17] = {0,128,293,495,734,882,1067,1289,1420,1588,
                               1793,2035,2186,2374,2599,2733,2904};

typedef __attribute__((ext_vector_type(8))) short short8;
typedef __attribute__((ext_vector_type(4))) float f32x4;
typedef __attribute__((ext_vector_type(4))) unsigned short ushort4v;

__device__ __forceinline__ unsigned short f2bf(float f) {
  __hip_bfloat16 h = __float2bfloat16(f);   // RNE
  return *reinterpret_cast<unsigned short*>(&h);
}
__device__ __forceinline__ float bf2f(unsigned short u) {
  union { unsigned int i; float f; } c; c.i = ((unsigned int)u) << 16; return c.f;
}
__device__ __forceinline__ float wred_sum(float x){
#pragma unroll
  for (int o = 32; o > 0; o >>= 1) x += __shfl_xor(x, o, 64);
  return x;
}

// async global->LDS, 16B per lane. LDS dest = wave-uniform base + lane*16.
__device__ __forceinline__ void gl_lds16(const unsigned short* g, unsigned short* l) {
  __builtin_amdgcn_global_load_lds(
      (const __attribute__((address_space(1))) unsigned int*)g,
      (__attribute__((address_space(3))) unsigned int*)l, 16, 0, 0);
}

// ---------------- fp32 -> bf16 pre-convert (5 segments) ----------------
__global__ __launch_bounds__(256) void cvt5(
    const float* __restrict__ s0, const float* __restrict__ s1,
    const float* __restrict__ s2, const float* __restrict__ s3,
    const float* __restrict__ s4,
    unsigned short* __restrict__ d0, unsigned short* __restrict__ d1,
    unsigned short* __restrict__ d2, unsigned short* __restrict__ d3,
    unsigned short* __restrict__ d4,
    int n0, int n1, int n2, int n3, int n4)
{
  const float* s; unsigned short* d; int n;
  switch (blockIdx.y) {
    case 0: s = s0; d = d0; n = n0; break;
    case 1: s = s1; d = d1; n = n1; break;
    case 2: s = s2; d = d2; n = n2; break;
    case 3: s = s3; d = d3; n = n3; break;
    default: s = s4; d = d4; n = n4; break;
  }
  const int i = (blockIdx.x * 256 + threadIdx.x) * 4;
  if (i < n) {
    const float4 v = *reinterpret_cast<const float4*>(s + i);
    ushort4v o = { f2bf(v.x), f2bf(v.y), f2bf(v.z), f2bf(v.w) };
    *reinterpret_cast<ushort4v*>(d + i) = o;
  }
}

// ================= MFMA GEMM: Y[M,N] = X[M,512] @ W[N,512]^T + bias ===========
// 128x128 tile, BK=64, 256 threads (4 waves 2x2), 4x4 frags/wave, 32 MFMA/K-step.
// LDS swizzle-order tiles: linear slot (row,cg) stores global col (cg^(row&7))*8.
// Epilogue: C tile repacked through LDS (reusing Xs/Ws) -> coalesced short8 stores.
template<int INF32>
__global__ __launch_bounds__(256) void gemm_tn(const void* __restrict__ Xv,
    const unsigned short* __restrict__ Wb, const float* __restrict__ bias,
    unsigned short* __restrict__ Yb, int M, int ldY)
{
  __shared__ unsigned short SMEM[2*128*64];   // Xs | Ws during K-loop; Cs after
  unsigned short* Xs = SMEM;
  unsigned short* Ws = SMEM + 128*64;
  const int tid = threadIdx.x, lane = tid & 63, w = tid >> 6;
  const int la = lane & 15, lg = lane >> 4;
  const int m0 = blockIdx.x * 128, n0 = blockIdx.y * 128;
  const int wm = (w & 1) * 64, wn = (w >> 1) * 64;
  const int w64 = w * 64;

  f32x4 acc[4][4];
#pragma unroll
  for (int i = 0; i < 4; ++i)
#pragma unroll
    for (int j = 0; j < 4; ++j) acc[i][j] = (f32x4){0.f,0.f,0.f,0.f};

  int elA[4][2], elB[4][2];
#pragma unroll
  for (int i = 0; i < 4; ++i)
#pragma unroll
    for (int kc = 0; kc < 2; ++kc) {
      { const int r = wm + i*16 + la;
        elA[i][kc] = r*64 + ((kc*32 + lg*8) ^ ((r & 7) << 3)); }
      { const int r = wn + i*16 + la;
        elB[i][kc] = r*64 + ((kc*32 + lg*8) ^ ((r & 7) << 3)); }
    }

  for (int kb = 0; kb < DD; kb += 64) {
    __syncthreads();
#pragma unroll
    for (int p = 0; p < 4; ++p) {
      const int slot = p*256 + tid;
      const int row = slot >> 3, cg = slot & 7;
      const int col = kb + ((cg ^ (row & 7)) << 3);
      gl_lds16(Wb + (size_t)(n0 + row) * DD + col, &Ws[(p*256 + w64) * 8]);
    }
    if (INF32) {
      const float* X = (const float*)Xv;
#pragma unroll
      for (int p = 0; p < 4; ++p) {
        const int slot = p*256 + tid;
        const int row = slot >> 3, cg = slot & 7;
        const int col = kb + ((cg ^ (row & 7)) << 3);
        const int rg = min(m0 + row, M - 1);
        const float* src = X + (size_t)rg * DD + col;
        const float4 v0 = *reinterpret_cast<const float4*>(src);
        const float4 v1 = *reinterpret_cast<const float4*>(src + 4);
        short8 pk;
        pk[0] = (short)f2bf(v0.x); pk[1] = (short)f2bf(v0.y);
        pk[2] = (short)f2bf(v0.z); pk[3] = (short)f2bf(v0.w);
        pk[4] = (short)f2bf(v1.x); pk[5] = (short)f2bf(v1.y);
        pk[6] = (short)f2bf(v1.z); pk[7] = (short)f2bf(v1.w);
        *reinterpret_cast<short8*>(&Xs[slot * 8]) = pk;
      }
    } else {
      const unsigned short* X = (const unsigned short*)Xv;
#pragma unroll
      for (int p = 0; p < 4; ++p) {
        const int slot = p*256 + tid;
        const int row = slot >> 3, cg = slot & 7;
        const int col = kb + ((cg ^ (row & 7)) << 3);
        const int rg = min(m0 + row, M - 1);
        gl_lds16(X + (size_t)rg * DD + col, &Xs[(p*256 + w64) * 8]);
      }
    }
    __syncthreads();

    short8 af[4][2], bfm[4][2];
#pragma unroll
    for (int i = 0; i < 4; ++i)
#pragma unroll
      for (int kc = 0; kc < 2; ++kc) {
        af[i][kc]  = *reinterpret_cast<const short8*>(&Xs[elA[i][kc]]);
        bfm[i][kc] = *reinterpret_cast<const short8*>(&Ws[elB[i][kc]]);
      }
#pragma unroll
    for (int kc = 0; kc < 2; ++kc)
#pragma unroll
      for (int i = 0; i < 4; ++i)
#pragma unroll
        for (int j = 0; j < 4; ++j)
          acc[i][j] = __builtin_amdgcn_mfma_f32_16x16x32_bf16(af[i][kc], bfm[j][kc], acc[i][j], 0, 0, 0);
  }

  // ---- epilogue: bias + repack through LDS -> coalesced 16B stores ----
  __syncthreads();                 // all frag ds_reads done
  unsigned short* Cs = SMEM;       // 128x128 bf16, swizzled rows
#pragma unroll
  for (int j = 0; j < 4; ++j) {
    const int n = wn + j*16 + la;
    const float bj = bias[n0 + n];
#pragma unroll
    for (int i = 0; i < 4; ++i) {
      const int mb = wm + i*16 + lg*4;
#pragma unroll
      for (int r = 0; r < 4; ++r) {
        const int m = mb + r;
        Cs[m*128 + (((n >> 3) ^ (m & 7)) << 3) + (n & 7)] = f2bf(acc[i][j][r] + bj);
      }
    }
  }
  __syncthreads();
#pragma unroll
  for (int p = 0; p < 8; ++p) {
    const int sid = p*256 + tid;
    const int row = sid >> 4, s = sid & 15;
    if (m0 + row < M) {
      const short8 v = *reinterpret_cast<const short8*>(&Cs[row*128 + ((s ^ (row & 7)) << 3)]);
      *reinterpret_cast<short8*>(Yb + (size_t)(m0 + row)*ldY + n0 + s*8) = v;
    }
  }
}

// ================= MFMA flash attention v3 (bf16, fp32 accum) =================
// grid (qtiles, B, H); block 256 = 4 waves; wave w owns 32 q-rows (2 m-frags).
// K/V staged in 256-key SUPER-chunks (2 barriers each); inner 64-key chunks run
// barrier-free (per-wave P buffer + wave_barrier). O repacked via LDS -> 16B stores.
template<int SWAP>
__global__ __launch_bounds__(256) void attn_v3(const unsigned short* __restrict__ Q,
                                               const unsigned short* __restrict__ K,
                                               const unsigned short* __restrict__ V,
                                               unsigned short* __restrict__ O, int ldkv)
{
  __shared__ unsigned short Ks[256*64];     // [key][d], swizzled (32 KB)
  __shared__ unsigned short Vt[64*256];     // [d][key], swizzled (32 KB)
  __shared__ unsigned short Pl[4][32*64];   // per-wave [qrow][key], swizzled (16 KB)
  const int* qo = SWAP ? c_roff : c_aoff;
  const int* ko = SWAP ? c_aoff : c_roff;
  const int b = blockIdx.y, h = blockIdx.z;
  const int Lq = qo[b+1]-qo[b], Lk = ko[b+1]-ko[b];
  const int q0 = blockIdx.x * 128;
  if (q0 >= Lq) return;
  const int tid = threadIdx.x, w = tid >> 6, lane = tid & 63;
  const int la = lane & 15, lg = lane >> 4;
  const unsigned short* Qb = Q + (size_t)qo[b]*DD + h*64;
  const unsigned short* Kb = K + (size_t)ko[b]*ldkv + h*64;
  const unsigned short* Vb = V + (size_t)ko[b]*ldkv + h*64;

  // Q A-frags: [i=m-frag][kc=d-chunk]; A[m=la][k=lg*8+e]
  short8 qf[2][2];
#pragma unroll
  for (int i = 0; i < 2; ++i) {
    const int qrow = q0 + w*32 + i*16 + la;
    if (qrow < Lq) {
      qf[i][0] = *reinterpret_cast<const short8*>(Qb + (size_t)qrow*DD + lg*8);
      qf[i][1] = *reinterpret_cast<const short8*>(Qb + (size_t)qrow*DD + 32 + lg*8);
    } else {
      qf[i][0] = (short8){0,0,0,0,0,0,0,0}; qf[i][1] = (short8){0,0,0,0,0,0,0,0};
    }
  }

  f32x4 acc[2][4];
#pragma unroll
  for (int i = 0; i < 2; ++i)
#pragma unroll
    for (int j = 0; j < 4; ++j) acc[i][j] = (f32x4){0.f,0.f,0.f,0.f};
  float mrun[2][4], lsum[2][4];
#pragma unroll
  for (int i = 0; i < 2; ++i)
#pragma unroll
    for (int r = 0; r < 4; ++r) { mrun[i][r] = -1e30f; lsum[i][r] = 0.f; }

  const int nsc = (Lk + 255) >> 8;
  for (int sc = 0; sc < nsc; ++sc) {
    const int kb0 = sc << 8;
    __syncthreads();               // prev super-chunk's LDS readers done
    // --- stage K: 256x64, 2048 slots, 8 gl_lds16/thread ---
#pragma unroll
    for (int p = 0; p < 8; ++p) {
      const int slot = p*256 + tid;
      const int row = slot >> 3, cg = slot & 7;
      const int rg = min(kb0 + row, Lk - 1);
      gl_lds16(Kb + (size_t)rg * ldkv + ((cg ^ (row & 7)) << 3),
               &Ks[(p*256 + w*64) * 8]);
    }
    // --- stage V transposed: [d][key], swizzled ---
#pragma unroll
    for (int p = 0; p < 4; ++p) {
      const int key = p*64 + (tid & 63);
      const int dg = tid >> 6;
      const int rg = min(kb0 + key, Lk - 1);
      const unsigned short* vp = Vb + (size_t)rg * ldkv + dg*16;
      const short8 v0 = *reinterpret_cast<const short8*>(vp);
      const short8 v1 = *reinterpret_cast<const short8*>(vp + 8);
#pragma unroll
      for (int e = 0; e < 8; ++e) {
        const int d0 = dg*16 + e, d1 = d0 + 8;
        Vt[d0*256 + (key ^ ((d0 & 7) << 3))] = (unsigned short)v0[e];
        Vt[d1*256 + (key ^ ((d1 & 7) << 3))] = (unsigned short)v1[e];
      }
    }
    __syncthreads();               // staging done (drains vmcnt + lgkm)

    const int cmax = min(4, (Lk - kb0 + 63) >> 6);
    for (int c = 0; c < cmax; ++c) {
      const int kbase = kb0 + c*64;
      // QK^T: B[k=d][n=key] from Ks rows (c*64 .. +63)
      short8 kf[4][2];
#pragma unroll
      for (int j = 0; j < 4; ++j)
#pragma unroll
        for (int k2 = 0; k2 < 2; ++k2) {
          const int row = c*64 + j*16 + la;
          kf[j][k2] = *reinterpret_cast<const short8*>(
              &Ks[row*64 + ((k2*32 + lg*8) ^ ((row & 7) << 3))]);
        }
      f32x4 S[2][4];
#pragma unroll
      for (int i = 0; i < 2; ++i)
#pragma unroll
        for (int j = 0; j < 4; ++j) {
          f32x4 s = (f32x4){0.f,0.f,0.f,0.f};
          s = __builtin_amdgcn_mfma_f32_16x16x32_bf16(qf[i][0], kf[j][0], s, 0, 0, 0);
          s = __builtin_amdgcn_mfma_f32_16x16x32_bf16(qf[i][1], kf[j][1], s, 0, 0, 0);
          S[i][j] = s;
        }

      // online softmax (C-layout: row = i*16+lg*4+r, col = j*16+la)
      float cm[2][4];
#pragma unroll
      for (int i = 0; i < 2; ++i)
#pragma unroll
        for (int r = 0; r < 4; ++r) {
          float m = -1e30f;
#pragma unroll
          for (int j = 0; j < 4; ++j) {
            const bool ok = (kbase + j*16 + la) < Lk;
            const float s = ok ? S[i][j][r] * 0.125f : -1e30f;
            S[i][j][r] = s;
            m = fmaxf(m, s);
          }
          cm[i][r] = m;
        }
#pragma unroll
      for (int msk = 1; msk <= 8; msk <<= 1)
#pragma unroll
        for (int i = 0; i < 2; ++i)
#pragma unroll
          for (int r = 0; r < 4; ++r) cm[i][r] = fmaxf(cm[i][r], __shfl_xor(cm[i][r], msk, 64));
#pragma unroll
      for (int i = 0; i < 2; ++i)
#pragma unroll
        for (int r = 0; r < 4; ++r) {
          const float mn = fmaxf(mrun[i][r], cm[i][r]);
          const float al = __expf(mrun[i][r] - mn);
          mrun[i][r] = mn;
          float psum = 0.f;
#pragma unroll
          for (int j = 0; j < 4; ++j) {
            const float p = __expf(S[i][j][r] - mn);
            S[i][j][r] = p;
            psum += p;
          }
          lsum[i][r] = lsum[i][r] * al + psum;
#pragma unroll
          for (int j = 0; j < 4; ++j) acc[i][j][r] *= al;
        }

      // P -> per-wave LDS (swizzled), then A-frags
#pragma unroll
      for (int i = 0; i < 2; ++i)
#pragma unroll
        for (int r = 0; r < 4; ++r) {
          const int prow = i*16 + lg*4 + r;
#pragma unroll
          for (int j = 0; j < 4; ++j)
            Pl[w][prow*64 + ((j*16 + la) ^ ((prow & 7) << 3))] = f2bf(S[i][j][r]);
        }
      __builtin_amdgcn_wave_barrier();   // per-wave LDS, in-order RAW

      short8 pf[2][2], vf[2][4];
#pragma unroll
      for (int i = 0; i < 2; ++i)
#pragma unroll
        for (int k2 = 0; k2 < 2; ++k2) {
          const int row = i*16 + la;
          pf[i][k2] = *reinterpret_cast<const short8*>(
              &Pl[w][row*64 + ((k2*32 + lg*8) ^ ((row & 7) << 3))]);
        }
#pragma unroll
      for (int k2 = 0; k2 < 2; ++k2)
#pragma unroll
        for (int j = 0; j < 4; ++j) {
          const int d = j*16 + la;
          vf[k2][j] = *reinterpret_cast<const short8*>(
              &Vt[d*256 + ((c*64 + k2*32 + lg*8) ^ ((d & 7) << 3))]);
        }
#pragma unroll
      for (int i = 0; i < 2; ++i)
#pragma unroll
        for (int j = 0; j < 4; ++j) {
          acc[i][j] = __builtin_amdgcn_mfma_f32_16x16x32_bf16(pf[i][0], vf[0][j], acc[i][j], 0, 0, 0);
          acc[i][j] = __builtin_amdgcn_mfma_f32_16x16x32_bf16(pf[i][1], vf[1][j], acc[i][j], 0, 0, 0);
        }
    }
  }

  // final row-sum over 16 la-lanes
#pragma unroll
  for (int msk = 1; msk <= 8; msk <<= 1)
#pragma unroll
    for (int i = 0; i < 2; ++i)
#pragma unroll
      for (int r = 0; r < 4; ++r) lsum[i][r] += __shfl_xor(lsum[i][r], msk, 64);

  // O repack: normalized acc -> per-wave LDS (swizzled) -> coalesced 16B stores
#pragma unroll
  for (int i = 0; i < 2; ++i)
#pragma unroll
    for (int r = 0; r < 4; ++r) {
      const float inv = 1.f / lsum[i][r];
      const int prow = i*16 + lg*4 + r;
#pragma unroll
      for (int j = 0; j < 4; ++j)
        Pl[w][prow*64 + ((j*16 + la) ^ ((prow & 7) << 3))] = f2bf(acc[i][j][r] * inv);
    }
  __builtin_amdgcn_wave_barrier();
#pragma unroll
  for (int p = 0; p < 4; ++p) {
    const int sid = p*64 + lane;          // 256 slots = 32 rows x 8
    const int row = sid >> 3, s = sid & 7;
    const int qrow = q0 + w*32 + row;
    if (qrow < Lq) {
      const short8 v = *reinterpret_cast<const short8*>(
          &Pl[w][row*64 + ((s ^ (row & 7)) << 3)]);
      *reinterpret_cast<short8*>(O + (size_t)(qo[b] + qrow)*DD + h*64 + s*8) = v;
    }
  }
}

// -------- LayerNorm over bf16 upd + fp32 residual -> fp32 d_out --------
__global__ __launch_bounds__(256) void ln_res(const unsigned short* __restrict__ Ub,
    float* __restrict__ Yout,
    const float* __restrict__ atom_node, const float* __restrict__ res_node,
    const float* __restrict__ ag, const float* __restrict__ ab,
    const float* __restrict__ rg, const float* __restrict__ rb)
{
  const int row = blockIdx.x * 4 + (threadIdx.x >> 6);
  const int lane = threadIdx.x & 63;
  if (row >= NA_TOT + NR_TOT) return;
  const float* g; const float* bb; const float* resid;
  if (row < NA_TOT) { g = ag; bb = ab; resid = atom_node + (size_t)row * DD; }
  else { g = rg; bb = rb; resid = res_node + (size_t)(row - NA_TOT) * DD; }
  const short8 xb = *reinterpret_cast<const short8*>(Ub + (size_t)row*DD + lane*8);
  float xv[8];
#pragma unroll
  for (int i = 0; i < 8; ++i) xv[i] = bf2f((unsigned short)xb[i]);
  float s = 0.f;
#pragma unroll
  for (int i = 0; i < 8; ++i) s += xv[i];
  s = wred_sum(s);
  const float mean = s * (1.f/512.f);
  float vs = 0.f;
#pragma unroll
  for (int i = 0; i < 8; ++i) { const float d = xv[i] - mean; vs = fmaf(d, d, vs); }
  vs = wred_sum(vs) * (1.f/512.f);
  const float inv = rsqrtf(vs + 1e-5f);
  const float4 g0 = *reinterpret_cast<const float4*>(g + lane*8);
  const float4 g1 = *reinterpret_cast<const float4*>(g + lane*8 + 4);
  const float4 b0 = *reinterpret_cast<const float4*>(bb + lane*8);
  const float4 b1 = *reinterpret_cast<const float4*>(bb + lane*8 + 4);
  const float4 r0 = *reinterpret_cast<const float4*>(resid + lane*8);
  const float4 r1 = *reinterpret_cast<const float4*>(resid + lane*8 + 4);
  float4 o0, o1;
  o0.x = (xv[0]-mean)*inv*g0.x + b0.x + r0.x;
  o0.y = (xv[1]-mean)*inv*g0.y + b0.y + r0.y;
  o0.z = (xv[2]-mean)*inv*g0.z + b0.z + r0.z;
  o0.w = (xv[3]-mean)*inv*g0.w + b0.w + r0.w;
  o1.x = (xv[4]-mean)*inv*g1.x + b1.x + r1.x;
  o1.y = (xv[5]-mean)*inv*g1.y + b1.y + r1.y;
  o1.z = (xv[6]-mean)*inv*g1.z + b1.z + r1.z;
  o1.w = (xv[7]-mean)*inv*g1.w + b1.w + r1.w;
  float* y = Yout + (size_t)row * DD + lane*8;
  *reinterpret_cast<float4*>(y)     = o0;
  *reinterpret_cast<float4*>(y + 4) = o1;
}

extern "C" void kernel_launch(void* const* d_in, const int* in_sizes, int n_in,
                              void* d_out, int out_size, void* d_ws, size_t ws_size,
                              hipStream_t stream) {
  (void)in_sizes; (void)n_in; (void)out_size; (void)ws_size;
  const float* atom_node = (const float*)d_in[0];
  const float* res_node  = (const float*)d_in[1];
  const float* r2a_in_w  = (const float*)d_in[2];
  const float* r2a_in_b  = (const float*)d_in[3];
  const float* r2a_out_w = (const float*)d_in[4];
  const float* r2a_out_b = (const float*)d_in[5];
  const float* a2r_in_w  = (const float*)d_in[6];
  const float* a2r_in_b  = (const float*)d_in[7];
  const float* a2r_out_w = (const float*)d_in[8];
  const float* a2r_out_b = (const float*)d_in[9];
  const float* atom_ln_g = (const float*)d_in[10];
  const float* atom_ln_b = (const float*)d_in[11];
  const float* res_ln_g  = (const float*)d_in[12];
  const float* res_ln_b  = (const float*)d_in[13];

  float* out = (float*)d_out;
  unsigned short* wsb = (unsigned short*)d_ws;
  const size_t NAD = (size_t)NA_TOT * DD;   // 11,726,848
  const size_t NRD = (size_t)NR_TOT * DD;   //  1,486,848
  // ws layout (shorts), phase-reused:
  unsigned short* Q1     = wsb;                          // [NAD]
  unsigned short* O1     = wsb + NAD;                    // [NAD]
  unsigned short* updb   = wsb + 2*NAD;                  // [NAD+NRD] atom_upd|res_upd bf16
  unsigned short* res_bf = wsb + 3*NAD + NRD;            // [NRD]
  unsigned short* KV1    = wsb + 3*NAD + 2*NRD;          // [2*NRD]
  unsigned short* wbf    = wsb + 3*NAD + 4*NRD;          // [2,097,152]
  unsigned short* w_r2a_in  = wbf;                       // 786432
  unsigned short* w_r2a_out = wbf +  786432;             // 262144
  unsigned short* w_a2r_in  = wbf + 1048576;             // 786432
  unsigned short* w_a2r_out = wbf + 1835008;             // 262144
  // reuses (lifetimes disjoint):
  unsigned short* KV2 = wsb;            // spans Q1+O1 (dead by then)
  unsigned short* Q2  = KV1;            // KV1 dead after attn1
  unsigned short* O2  = KV1 + NRD;

  const dim3 blk(256);
  const int gma = (NA_TOT + 127) / 128;  // 179
  const int gmr = (NR_TOT + 127) / 128;  // 23

  // --- pre-convert weights + res_node to bf16
  cvt5<<<dim3(1452, 5), blk, 0, stream>>>(
      r2a_in_w, r2a_out_w, a2r_in_w, a2r_out_w, res_node,
      w_r2a_in, w_r2a_out, w_a2r_in, w_a2r_out, res_bf,
      786432, 262144, 786432, 262144, (int)NRD);

  // --- mha1 (res -> atom)
  gemm_tn<1><<<dim3(gma,4), blk, 0, stream>>>(atom_node, w_r2a_in,          r2a_in_b,       Q1,  NA_TOT, 512);
  gemm_tn<0><<<dim3(gmr,8), blk, 0, stream>>>(res_bf,    w_r2a_in + 262144, r2a_in_b + 512, KV1, NR_TOT, 1024);
  attn_v3<0><<<dim3(16,16,8), blk, 0, stream>>>(Q1, KV1, KV1 + 512, O1, 1024);
  gemm_tn<0><<<dim3(gma,4), blk, 0, stream>>>(O1, w_r2a_out, r2a_out_b, updb, NA_TOT, 512);

  // --- mha2 (atom -> res)
  gemm_tn<0><<<dim3(gmr,4), blk, 0, stream>>>(res_bf, w_a2r_in,          a2r_in_b,       Q2,  NR_TOT, 512);
  gemm_tn<0><<<dim3(gma,8), blk, 0, stream>>>(updb,   w_a2r_in + 262144, a2r_in_b + 512, KV2, NA_TOT, 1024);
  attn_v3<1><<<dim3(2,16,8), blk, 0, stream>>>(Q2, KV2, KV2 + 512, O2, 1024);
  gemm_tn<0><<<dim3(gmr,4), blk, 0, stream>>>(O2, w_a2r_out, a2r_out_b, updb + NAD, NR_TOT, 512);

  // --- LayerNorm (bf16 upd) + fp32 residual -> d_out
  ln_res<<<dim3((NA_TOT + NR_TOT + 3) / 4), blk, 0, stream>>>(
      updb, out, atom_node, res_node, atom_ln_g, atom_ln_b, res_ln_g, res_ln_b);
}